// Round 1
// 805.928 us; speedup vs baseline: 1.1023x; 1.1023x over previous
//
#include <hip/hip_runtime.h>
#include <math.h>

// ---------------------------------------------------------------------------
// LongRec.  B=256, S=200, D=U=128, NC=50000.
// alpha = softmax over singleton axis == 1.0 -> h_att = h_d; W_a is dead.
// Pipeline:
//   k0  : 128x128 weights fp32 -> bf16 k-swizzled for MFMA B-frags
//   k12 : MFMA precompute (wave-local LDS, no barriers) -> PRE fp32
//   k3  : 200-step recurrence, 1 wg/row, 768 thr = 3 matrices x 256 thr.
//         R6 re-tile: each matvec thread owns 4 cols x 16 k (was 1x64) ->
//         4 ds_read_b128 broadcasts/thread instead of 16; per-step LDS
//         instruction count drops ~4x (192 -> ~60).  64 weights/thread
//         pinned in VGPRs via opaque asm.  4 lgkm-only barriers/step.
//   k0b : W_out -> bf16 WT[n][k]  (aliases PRE, dead after k3)
//   k4a : logits = h @ W_out + b_out via bf16 MFMA
//   k4b/c: row stats, softmax normalize
// ---------------------------------------------------------------------------

#define B_  256
#define S_  200
#define U_  128
#define NC  50000
#define NTOK (B_ * S_)       // 51200

// ws layout (in floats)
#define PRE_OFF   0
#define PRE_SZ    (NTOK * 768)            // 39321600 floats
#define LOG_OFF   PRE_SZ                  // logits: 12.8M floats
#define WSWZ_OFF  (PRE_SZ + 12800000)     // bf16 weights: 12*16384 ushort
#define HF_OFF    (PRE_SZ + 13107200)
#define RMAX_OFF  (HF_OFF + B_ * U_)
#define RSUM_OFF  (RMAX_OFF + B_)
// WT (bf16 W_out^T) aliases PRE_OFF — PRE dead after k3; k0b runs after k3.

// PRE per-token layout: [decay(0) | xr(128) | xz(256) | xh(384) | fdir(512) | psi(640)]

typedef float  float4v  __attribute__((ext_vector_type(4)));
typedef short  short8v  __attribute__((ext_vector_type(8)));

__device__ __forceinline__ float sigmoidf_(float x) {
    if (x >= 0.f) { return 1.f / (1.f + expf(-x)); }
    float e = expf(x); return e / (1.f + e);
}
__device__ __forceinline__ float softplusf_(float x) {
    return fmaxf(x, 0.f) + log1pf(expf(-fabsf(x)));
}
__device__ __forceinline__ unsigned short f2bf(float f) {   // RNE
    unsigned int u = __float_as_uint(f);
    u = (u + 0x7fffu + ((u >> 16) & 1u)) >> 16;
    return (unsigned short)u;
}
__device__ __forceinline__ unsigned int pack2bf(float a, float b) {
    return (unsigned int)f2bf(a) | ((unsigned int)f2bf(b) << 16);
}
// Barrier draining only LDS (lgkmcnt) — global prefetches stay in flight.
__device__ __forceinline__ void bar_lds() {
    asm volatile("s_waitcnt lgkmcnt(0)\n\ts_barrier" ::: "memory");
}

// ---------------------------------------------------------------------------
// k0: 12 x [128][128] fp32 -> bf16 swizzled  dst[((k>>5)*128 + n)*32 + (k&31)]
__global__ __launch_bounds__(256) void k0_wconv(
    const float* s0, const float* s1, const float* s2, const float* s3,
    const float* s4, const float* s5, const float* s6, const float* s7,
    const float* s8, const float* s9, const float* s10, const float* s11,
    unsigned short* __restrict__ dst)
{
    const float* srcs[12] = { s0,s1,s2,s3,s4,s5,s6,s7,s8,s9,s10,s11 };
    const float* S = srcs[blockIdx.x];
    unsigned short* D = dst + (size_t)blockIdx.x * 16384;
    for (int i = threadIdx.x; i < 16384; i += 256) {
        int k5 = i & 31, n = (i >> 5) & 127, kb = i >> 12;
        D[i] = f2bf(S[(size_t)(kb * 32 + k5) * 128 + n]);
    }
}

// ---------------------------------------------------------------------------
// k0b: W_out [128][50000] fp32 -> WT [n][k] bf16
__global__ __launch_bounds__(256) void k0b_woutT(const float* __restrict__ W_out,
                                                 unsigned short* __restrict__ WT)
{
    int n  = blockIdx.x * 64 + (threadIdx.x >> 2);
    int k0 = (threadIdx.x & 3) * 32;
    if (n >= NC) return;
#pragma unroll 8
    for (int i = 0; i < 32; ++i)
        WT[(size_t)n * 128 + k0 + i] = f2bf(W_out[(size_t)(k0 + i) * NC + n]);
}

// ---------------------------------------------------------------------------
// MFMA helpers (16x16x32 bf16).  A-frag: lane holds A[m0+(lane&15)][kb*32+quad*8+j].
// B-frag (swizzled W): lane holds W[kb*32+quad*8+j][nt*16+(lane&15)].
// C/D: col = lane&15, row = quad*4 + reg.
__device__ __forceinline__ void gemm_k128(const unsigned short (*A)[136],
                                          int m0, int l16, int quad,
                                          const unsigned short* __restrict__ Wm,
                                          float4v acc[8]) {
#pragma unroll
    for (int kb = 0; kb < 4; ++kb) {
        short8v av = *(const short8v*)&A[m0 + l16][kb * 32 + quad * 8];
#pragma unroll
        for (int nt = 0; nt < 8; ++nt) {
            short8v bv = *(const short8v*)(Wm + (((kb * 128) + nt * 16 + l16) * 32 + quad * 8));
            acc[nt] = __builtin_amdgcn_mfma_f32_16x16x32_bf16(av, bv, acc[nt], 0, 0, 0);
        }
    }
}
__device__ __forceinline__ void zero8(float4v acc[8]) {
#pragma unroll
    for (int i = 0; i < 8; ++i) acc[i] = (float4v)0.0f;
}

// ---------------------------------------------------------------------------
// k12: fused MFMA precompute.  grid = NTOK/64, block = 256 (4 waves).
__global__ __launch_bounds__(256) void k12_precompute(
    const int* __restrict__ item, const int* __restrict__ tix, const int* __restrict__ frq,
    const float* __restrict__ Ei, const float* __restrict__ Et, const float* __restrict__ Ef,
    const float* __restrict__ b_r, const float* __restrict__ b_z, const float* __restrict__ b_h,
    const float* __restrict__ b_tg, const float* __restrict__ b_fg,
    const float* __restrict__ b_delta, const float* __restrict__ b_f_dir, const float* __restrict__ b_psi,
    const unsigned short* __restrict__ WZ,
    float* __restrict__ PRE)
{
    __shared__ unsigned short Axi[64][136];   // xi
    __shared__ unsigned short Axb[64][136];   // xt -> tg
    __shared__ unsigned short Axc[64][136];   // xf -> fg

    const int t0  = blockIdx.x * 64;
    const int tid = threadIdx.x;

    // Staging: rows are WAVE-LOCAL (wave w stages rows 16w..16w+15 and only
    // ever reads/writes those rows => no barriers needed in this kernel).
    {
        const int row  = tid >> 2;
        const int part = tid & 3;
        const int tok  = t0 + row;
        const float* pei = Ei + (size_t)item[tok] * U_ + part * 32;
        const float* pet = Et + (size_t)tix[tok]  * U_ + part * 32;
        const float* pef = Ef + (size_t)frq[tok]  * U_ + part * 32;
#pragma unroll
        for (int i = 0; i < 8; ++i) {
            float4 v = *(const float4*)(pei + i * 4);
            *(uint2*)&Axi[row][part * 32 + i * 4] = make_uint2(pack2bf(v.x, v.y), pack2bf(v.z, v.w));
            v = *(const float4*)(pet + i * 4);
            *(uint2*)&Axb[row][part * 32 + i * 4] = make_uint2(pack2bf(v.x, v.y), pack2bf(v.z, v.w));
            v = *(const float4*)(pef + i * 4);
            *(uint2*)&Axc[row][part * 32 + i * 4] = make_uint2(pack2bf(v.x, v.y), pack2bf(v.z, v.w));
        }
    }

    const int lane = tid & 63;
    const int wid  = tid >> 6;
    const int quad = lane >> 4;
    const int l16  = lane & 15;
    const int m0   = wid * 16;

    const unsigned short* WM0  = WZ;                 // W_xtg
    const unsigned short* WM1  = WZ + 1  * 16384;    // W_tg
    const unsigned short* WM2  = WZ + 2  * 16384;    // W_xfg
    const unsigned short* WM3  = WZ + 3  * 16384;    // W_fg
    const unsigned short* WM4  = WZ + 4  * 16384;    // W_xr
    const unsigned short* WM5  = WZ + 5  * 16384;    // W_xz
    const unsigned short* WM6  = WZ + 6  * 16384;    // W_xh
    const unsigned short* WM7  = WZ + 7  * 16384;    // W_delta top (tg rows)
    const unsigned short* WM8  = WZ + 8  * 16384;    // W_delta bot (fg rows)
    const unsigned short* WM9  = WZ + 9  * 16384;    // W_f_dir
    const unsigned short* WM10 = WZ + 10 * 16384;    // W_psi

    float4v acc[8];

    // ---- tg = sigmoid(xi@W_xtg + xt@W_tg + b_tg) -> Axb (bf16, A-layout) ----
    zero8(acc);
    gemm_k128(Axi, m0, l16, quad, WM0, acc);
    gemm_k128(Axb, m0, l16, quad, WM1, acc);
#pragma unroll
    for (int nt = 0; nt < 8; ++nt) {
        int n = nt * 16 + l16;
        float bb = b_tg[n];
#pragma unroll
        for (int r = 0; r < 4; ++r)
            Axb[m0 + quad * 4 + r][n] = f2bf(sigmoidf_(acc[nt][r] + bb));
    }
    // ---- fg = sigmoid(xi@W_xfg + xf@W_fg + b_fg) -> Axc ----
    zero8(acc);
    gemm_k128(Axi, m0, l16, quad, WM2, acc);
    gemm_k128(Axc, m0, l16, quad, WM3, acc);
#pragma unroll
    for (int nt = 0; nt < 8; ++nt) {
        int n = nt * 16 + l16;
        float bb = b_fg[n];
#pragma unroll
        for (int r = 0; r < 4; ++r)
            Axc[m0 + quad * 4 + r][n] = f2bf(sigmoidf_(acc[nt][r] + bb));
    }

    const int tokbase = t0 + m0 + quad * 4;

    // ---- xr, xz, xh ----
    {
        const unsigned short* Wx[3] = { WM4, WM5, WM6 };
        const float* bx[3] = { b_r, b_z, b_h };
        const int    off[3] = { 128, 256, 384 };
#pragma unroll
        for (int m = 0; m < 3; ++m) {
            zero8(acc);
            gemm_k128(Axi, m0, l16, quad, Wx[m], acc);
#pragma unroll
            for (int nt = 0; nt < 8; ++nt) {
                int n = nt * 16 + l16;
                float bb = bx[m][n];
#pragma unroll
                for (int r = 0; r < 4; ++r)
                    PRE[(size_t)(tokbase + r) * 768 + off[m] + n] = acc[nt][r] + bb;
            }
        }
    }
    // ---- decay = exp(-softplus([tg|fg]@W_delta + b_delta)) ----
    zero8(acc);
    gemm_k128(Axb, m0, l16, quad, WM7, acc);
    gemm_k128(Axc, m0, l16, quad, WM8, acc);
#pragma unroll
    for (int nt = 0; nt < 8; ++nt) {
        int n = nt * 16 + l16;
        float bb = b_delta[n];
#pragma unroll
        for (int r = 0; r < 4; ++r)
            PRE[(size_t)(tokbase + r) * 768 + 0 + n] = expf(-softplusf_(acc[nt][r] + bb));
    }
    // ---- fdir = fg@W_f_dir + b ----
    zero8(acc);
    gemm_k128(Axc, m0, l16, quad, WM9, acc);
#pragma unroll
    for (int nt = 0; nt < 8; ++nt) {
        int n = nt * 16 + l16;
        float bb = b_f_dir[n];
#pragma unroll
        for (int r = 0; r < 4; ++r)
            PRE[(size_t)(tokbase + r) * 768 + 512 + n] = acc[nt][r] + bb;
    }
    // ---- psi = sigmoid(fg@W_psi + b) ----
    zero8(acc);
    gemm_k128(Axc, m0, l16, quad, WM10, acc);
#pragma unroll
    for (int nt = 0; nt < 8; ++nt) {
        int n = nt * 16 + l16;
        float bb = b_psi[n];
#pragma unroll
        for (int r = 0; r < 4; ++r)
            PRE[(size_t)(tokbase + r) * 768 + 640 + n] = sigmoidf_(acc[nt][r] + bb);
    }
}

// ---------------------------------------------------------------------------
// k3: one workgroup per batch row; 768 threads = 3 matrices x 256 threads.
//   tid>>8 : 0 -> W_hr, 1 -> W_hz, 2 -> W_hh
//   Within a matrix: thread owns 4 consecutive output cols x 16 k-rows
//   (col0 = (t&31)*4, kr = t>>5).  FMA count/thread unchanged (64) but the
//   vector re-read is 4 ds_read_b128 broadcasts instead of 16 — the per-step
//   LDS-issue storm was the measured bottleneck (VALUBusy 33%, HBM 3%).
//   k-split is 8-way -> partials p*[8][128]; combines are 8 conflict-free
//   scalar reads by one 128-thread group.
//   Roles: B2: grp4 -> rh, grp0 -> zb.  C2: grp2 -> h update + Hb write.
//   Step: B(r,z partials) / B2(rh,zb) / C(h partials) / C2(h update) with
//   lgkm-only barriers; PRE prefetch stays in vmcnt flight.
__global__ __launch_bounds__(768, 2) void k3_scan(
    const float* __restrict__ PRE,
    const float* __restrict__ W_hr, const float* __restrict__ W_hz, const float* __restrict__ W_hh,
    unsigned short* __restrict__ Hb)
{
    const int b     = blockIdx.x;
    const int tid   = threadIdx.x;
    const int mat   = tid >> 8;         // 0: W_hr, 1: W_hz, 2: W_hh
    const int t     = tid & 255;
    const int col0  = (t & 31) << 2;    // 4 consecutive output columns
    const int kr    = t >> 5;           // k-range index, 8-way split
    const int kbase = kr << 4;          // [kbase, kbase+16)
    const int grp   = tid >> 7;         // 0..5 (128-thread combine roles)
    const int u     = tid & 127;

    const float* W = (mat == 0) ? W_hr : ((mat == 1) ? W_hz : W_hh);
    float wc[64];                       // wc[kk*4+c] = W[kbase+kk][col0+c]
#pragma unroll
    for (int k = 0; k < 16; ++k) {
        float4 wv = *(const float4*)&W[(size_t)(kbase + k) * U_ + col0];
        wc[k * 4 + 0] = wv.x; wc[k * 4 + 1] = wv.y;
        wc[k * 4 + 2] = wv.z; wc[k * 4 + 3] = wv.w;
    }
#pragma unroll
    for (int k = 0; k < 64; ++k) asm volatile("" : "+v"(wc[k]));   // pin in VGPRs

    __shared__ __align__(16) float hd[U_];
    __shared__ __align__(16) float rh[U_];
    __shared__ __align__(16) float zb[U_];
    __shared__ __align__(16) float pr[8][U_];
    __shared__ __align__(16) float pz[8][U_];
    __shared__ __align__(16) float ph[8][U_];
    if (tid < U_) hd[tid] = 0.f;    // h0 = 0 -> h_d(step 0) = 0

    const float* pre = PRE + (size_t)b * S_ * 768;
    // loop-carried per-group scalars (c*) and h state (grp 2 only)
    float c0 = 0.f, c1 = 0.f, c2 = 0.f, c3 = 0.f, hn = 0.f;
    {
        if (grp == 4)      c0 = pre[128 + u];                        // xr[0]
        else if (grp == 0) c0 = pre[256 + u];                        // xz[0]
        else if (grp == 2) { c0 = pre[384 + u]; c1 = pre[512 + u];   // xh, fdir
                             c2 = pre[640 + u];                      // psi
                             c3 = pre[768 + u]; }                    // decay[1]
    }
    bar_lds();

// 16k x 4col FMA block over vector VSRC, result -> DST[kr][col0..col0+3]
#define MATVEC16X4(VSRC, DST) do {                                          \
    float a0 = 0.f, a1 = 0.f, a2 = 0.f, a3 = 0.f;                           \
    _Pragma("unroll")                                                       \
    for (int q = 0; q < 4; ++q) {                                           \
        float4 hv = *(const float4*)&VSRC[kbase + 4 * q];                   \
        a0 = fmaf(hv.x, wc[(4*q+0)*4+0], a0);                               \
        a1 = fmaf(hv.x, wc[(4*q+0)*4+1], a1);                               \
        a2 = fmaf(hv.x, wc[(4*q+0)*4+2], a2);                               \
        a3 = fmaf(hv.x, wc[(4*q+0)*4+3], a3);                               \
        a0 = fmaf(hv.y, wc[(4*q+1)*4+0], a0);                               \
        a1 = fmaf(hv.y, wc[(4*q+1)*4+1], a1);                               \
        a2 = fmaf(hv.y, wc[(4*q+1)*4+2], a2);                               \
        a3 = fmaf(hv.y, wc[(4*q+1)*4+3], a3);                               \
        a0 = fmaf(hv.z, wc[(4*q+2)*4+0], a0);                               \
        a1 = fmaf(hv.z, wc[(4*q+2)*4+1], a1);                               \
        a2 = fmaf(hv.z, wc[(4*q+2)*4+2], a2);                               \
        a3 = fmaf(hv.z, wc[(4*q+2)*4+3], a3);                               \
        a0 = fmaf(hv.w, wc[(4*q+3)*4+0], a0);                               \
        a1 = fmaf(hv.w, wc[(4*q+3)*4+1], a1);                               \
        a2 = fmaf(hv.w, wc[(4*q+3)*4+2], a2);                               \
        a3 = fmaf(hv.w, wc[(4*q+3)*4+3], a3);                               \
    }                                                                       \
    float4 o_; o_.x = a0; o_.y = a1; o_.z = a2; o_.w = a3;                  \
    *(float4*)&DST[kr][col0] = o_;                                          \
} while (0)

    for (int s = 0; s < S_; ++s) {
        // prefetch step s+1 (left in vmcnt flight across all 4 barriers)
        float n0 = 0.f, n1 = 0.f, n2 = 0.f, n3 = 0.f;
        if (s + 1 < S_) {
            const float* p = pre + (size_t)(s + 1) * 768;
            if (grp == 4)      n0 = p[128 + u];
            else if (grp == 0) n0 = p[256 + u];
            else if (grp == 2) { n0 = p[384 + u]; n1 = p[512 + u]; n2 = p[640 + u];
                                 n3 = (s + 2 < S_) ? pre[(size_t)(s + 2) * 768 + u] : 0.f; }
        }

        // Phase B: r- and z-matvec partials over hd
        if (mat == 0)      MATVEC16X4(hd, pr);
        else if (mat == 1) MATVEC16X4(hd, pz);
        bar_lds();   // pr, pz ready

        // Phase B2: combine r (grp4) and z (grp0)
        if (grp == 4) {
            float srt = c0;
#pragma unroll
            for (int i = 0; i < 8; ++i) srt += pr[i][u];
            rh[u] = sigmoidf_(srt) * hd[u];
        } else if (grp == 0) {
            float szt = c0;
#pragma unroll
            for (int i = 0; i < 8; ++i) szt += pz[i][u];
            zb[u] = sigmoidf_(szt);
        }
        bar_lds();   // rh, zb ready

        // Phase C: h-matvec partials over rh
        if (mat == 2) MATVEC16X4(rh, ph);
        bar_lds();   // ph ready

        // Phase C2: h update (grp 2 only)
        if (grp == 2) {
            float mv2 = 0.f;
#pragma unroll
            for (int i = 0; i < 8; ++i) mv2 += ph[i][u];
            float hb = tanhf(c0 + mv2);
            float hf = tanhf(hb + c1);
            float hc = (1.f - c2) * hb + c2 * hf;
            float z  = zb[u];
            hn = (1.f - z) * hd[u] + z * hc;   // alpha==1 -> h_att = h_d
            hd[u] = c3 * hn;                    // decay[s+1] * h_new
        }
        bar_lds();   // hd ready for next step

        c0 = n0; c1 = n1; c2 = n2; c3 = n3;
    }
#undef MATVEC16X4
    if (grp == 2) Hb[(size_t)b * U_ + u] = f2bf(hn);
}

// ---------------------------------------------------------------------------
// k4a: logits = h @ W_out + b_out via bf16 MFMA.
__global__ __launch_bounds__(256) void k4a_logits(
    const unsigned short* __restrict__ Hb, const unsigned short* __restrict__ WT,
    const float* __restrict__ b_out, float* __restrict__ logits)
{
    const int tid  = threadIdx.x;
    const int lane = tid & 63, wid = tid >> 6;
    const int quad = lane >> 4, l16 = lane & 15;
    const int rb = blockIdx.y * 64 + wid * 16;
    const int cb = blockIdx.x * 128;

    short8v av[4];
#pragma unroll
    for (int kb = 0; kb < 4; ++kb)
        av[kb] = *(const short8v*)&Hb[(size_t)(rb + l16) * 128 + kb * 32 + quad * 8];

    float4v acc[8];
#pragma unroll
    for (int i = 0; i < 8; ++i) acc[i] = (float4v)0.0f;

#pragma unroll
    for (int kb = 0; kb < 4; ++kb) {
#pragma unroll
        for (int nt = 0; nt < 8; ++nt) {
            short8v bv = *(const short8v*)&WT[(size_t)(cb + nt * 16 + l16) * 128 + kb * 32 + quad * 8];
            acc[nt] = __builtin_amdgcn_mfma_f32_16x16x32_bf16(av[kb], bv, acc[nt], 0, 0, 0);
        }
    }
#pragma unroll
    for (int nt = 0; nt < 8; ++nt) {
        int n = cb + nt * 16 + l16;
        if (n < NC) {
            float bb = b_out[n];
#pragma unroll
            for (int r = 0; r < 4; ++r)
                logits[(size_t)(rb + quad * 4 + r) * NC + n] = acc[nt][r] + bb;
        }
    }
}

// ---------------------------------------------------------------------------
__global__ __launch_bounds__(256) void k4b_rowstats(
    const float* __restrict__ logits, float* __restrict__ rmax, float* __restrict__ rsum)
{
    const int r = blockIdx.x;
    const int tid = threadIdx.x;
    const float* row = logits + (size_t)r * NC;

    float m = -INFINITY, s = 0.f;
    for (int c = tid; c < NC; c += 256) {
        float x = row[c];
        float mn = fmaxf(m, x);
        s = s * expf(m - mn) + expf(x - mn);
        m = mn;
    }
    __shared__ float sm[256], ss[256];
    sm[tid] = m; ss[tid] = s;
    __syncthreads();
    for (int off = 128; off > 0; off >>= 1) {
        if (tid < off) {
            float m2 = sm[tid + off], s2 = ss[tid + off];
            float M = fmaxf(sm[tid], m2);
            ss[tid] = ss[tid] * expf(sm[tid] - M) + s2 * expf(m2 - M);
            sm[tid] = M;
        }
        __syncthreads();
    }
    if (tid == 0) { rmax[r] = sm[0]; rsum[r] = ss[0]; }
}

__global__ __launch_bounds__(256) void k4c_norm(
    const float* __restrict__ logits, const float* __restrict__ rmax,
    const float* __restrict__ rsum, float* __restrict__ out)
{
    const int r = blockIdx.y;
    const int c = blockIdx.x * 256 + threadIdx.x;
    if (c < NC) {
        size_t i = (size_t)r * NC + c;
        out[i] = expf(logits[i] - rmax[r]) / rsum[r];
    }
}

// ---------------------------------------------------------------------------
extern "C" void kernel_launch(void* const* d_in, const int* in_sizes, int n_in,
                              void* d_out, int out_size, void* d_ws, size_t ws_size,
                              hipStream_t stream) {
    const int*   item   = (const int*)d_in[0];
    const int*   tix    = (const int*)d_in[1];
    const int*   frq    = (const int*)d_in[2];
    const float* Ei     = (const float*)d_in[3];
    const float* Et     = (const float*)d_in[4];
    const float* Ef     = (const float*)d_in[5];
    const float* W_xr   = (const float*)d_in[6];
    const float* W_hr   = (const float*)d_in[7];
    const float* b_r    = (const float*)d_in[8];
    const float* W_xz   = (const float*)d_in[9];
    const float* W_hz   = (const float*)d_in[10];
    const float* b_z    = (const float*)d_in[11];
    const float* W_xh   = (const float*)d_in[12];
    const float* W_hh   = (const float*)d_in[13];
    const float* b_h    = (const float*)d_in[14];
    const float* W_xtg  = (const float*)d_in[15];
    const float* W_tg   = (const float*)d_in[16];
    const float* b_tg   = (const float*)d_in[17];
    const float* W_xfg  = (const float*)d_in[18];
    const float* W_fg   = (const float*)d_in[19];
    const float* b_fg   = (const float*)d_in[20];
    const float* W_delta= (const float*)d_in[21];
    const float* b_delta= (const float*)d_in[22];
    const float* W_f_dir= (const float*)d_in[23];
    const float* b_f_dir= (const float*)d_in[24];
    const float* W_psi  = (const float*)d_in[25];
    const float* b_psi  = (const float*)d_in[26];
    // d_in[27] = W_a — dead (softmax over singleton axis == 1)
    const float* W_out  = (const float*)d_in[28];
    const float* b_out  = (const float*)d_in[29];
    float* out = (float*)d_out;

    float* ws   = (float*)d_ws;
    float* PRE  = ws + PRE_OFF;
    float* LOG  = ws + LOG_OFF;
    unsigned short* WSWZ = (unsigned short*)(ws + WSWZ_OFF);
    unsigned short* WT   = (unsigned short*)(ws + PRE_OFF);   // aliases PRE (dead after k3)
    unsigned short* Hb   = (unsigned short*)(ws + HF_OFF);
    float* RMAX = ws + RMAX_OFF;
    float* RSUM = ws + RSUM_OFF;

    k0_wconv<<<12, 256, 0, stream>>>(
        W_xtg, W_tg, W_xfg, W_fg, W_xr, W_xz, W_xh,
        W_delta, W_delta + 128 * 128, W_f_dir, W_psi,
        W_psi /* pad slot 11, unused by k12 */, WSWZ);
    k12_precompute<<<NTOK / 64, 256, 0, stream>>>(
        item, tix, frq, Ei, Et, Ef,
        b_r, b_z, b_h, b_tg, b_fg, b_delta, b_f_dir, b_psi,
        WSWZ, PRE);
    k3_scan<<<B_, 768, 0, stream>>>(PRE, W_hr, W_hz, W_hh, Hb);
    k0b_woutT<<<(NC + 63) / 64, 256, 0, stream>>>(W_out, WT);
    k4a_logits<<<dim3((NC + 127) / 128, B_ / 64), 256, 0, stream>>>(Hb, WT, b_out, LOG);
    k4b_rowstats<<<B_, 256, 0, stream>>>(LOG, RMAX, RSUM);
    k4c_norm<<<dim3((NC + 255) / 256, B_), 256, 0, stream>>>(LOG, RMAX, RSUM, out);
}

// Round 2
// 683.079 us; speedup vs baseline: 1.3005x; 1.1798x over previous
//
#include <hip/hip_runtime.h>
#include <math.h>

// ---------------------------------------------------------------------------
// LongRec.  B=256, S=200, D=U=128, NC=50000.
// alpha = softmax over singleton axis == 1.0 -> h_att = h_d; W_a is dead.
// Pipeline:
//   k0  : 128x128 weights fp32 -> bf16 k-swizzled for MFMA B-frags
//   k12 : MFMA precompute -> PRE fp32.  R7: embeddings gathered DIRECTLY into
//         register A-frags (A-frag layout == gathered row layout), no staging
//         LDS; only tg/fg keep an LDS transpose round-trip (35 KB -> 4 wg/CU,
//         16 waves/CU vs 12 before; was latency-bound at Occ 21%).
//   k3  : 200-step recurrence, 1 wg/row, 768 thr = 3 matrices x 256 thr;
//         4 cols x 16 k per thread; 64 weights/thread pinned in VGPRs.
//   k0b : W_out -> bf16 WT[n][k]  (aliases PRE, dead after k3)
//   k4a : logits = h @ W_out + b_out via bf16 MFMA
//   k4b/c: row stats, softmax normalize
// ---------------------------------------------------------------------------

#define B_  256
#define S_  200
#define U_  128
#define NC  50000
#define NTOK (B_ * S_)       // 51200

// ws layout (in floats)
#define PRE_OFF   0
#define PRE_SZ    (NTOK * 768)            // 39321600 floats
#define LOG_OFF   PRE_SZ                  // logits: 12.8M floats
#define WSWZ_OFF  (PRE_SZ + 12800000)     // bf16 weights: 12*16384 ushort
#define HF_OFF    (PRE_SZ + 13107200)
#define RMAX_OFF  (HF_OFF + B_ * U_)
#define RSUM_OFF  (RMAX_OFF + B_)
// WT (bf16 W_out^T) aliases PRE_OFF — PRE dead after k3; k0b runs after k3.

// PRE per-token layout: [decay(0) | xr(128) | xz(256) | xh(384) | fdir(512) | psi(640)]

typedef float  float4v  __attribute__((ext_vector_type(4)));
typedef short  short8v  __attribute__((ext_vector_type(8)));

__device__ __forceinline__ float sigmoidf_(float x) {
    if (x >= 0.f) { return 1.f / (1.f + expf(-x)); }
    float e = expf(x); return e / (1.f + e);
}
__device__ __forceinline__ float softplusf_(float x) {
    return fmaxf(x, 0.f) + log1pf(expf(-fabsf(x)));
}
__device__ __forceinline__ unsigned short f2bf(float f) {   // RNE
    unsigned int u = __float_as_uint(f);
    u = (u + 0x7fffu + ((u >> 16) & 1u)) >> 16;
    return (unsigned short)u;
}
__device__ __forceinline__ unsigned int pack2bf(float a, float b) {
    return (unsigned int)f2bf(a) | ((unsigned int)f2bf(b) << 16);
}
// Barrier draining only LDS (lgkmcnt) — global prefetches stay in flight.
__device__ __forceinline__ void bar_lds() {
    asm volatile("s_waitcnt lgkmcnt(0)\n\ts_barrier" ::: "memory");
}

// ---------------------------------------------------------------------------
// k0: 12 x [128][128] fp32 -> bf16 swizzled  dst[((k>>5)*128 + n)*32 + (k&31)]
__global__ __launch_bounds__(256) void k0_wconv(
    const float* s0, const float* s1, const float* s2, const float* s3,
    const float* s4, const float* s5, const float* s6, const float* s7,
    const float* s8, const float* s9, const float* s10, const float* s11,
    unsigned short* __restrict__ dst)
{
    const float* srcs[12] = { s0,s1,s2,s3,s4,s5,s6,s7,s8,s9,s10,s11 };
    const float* S = srcs[blockIdx.x];
    unsigned short* D = dst + (size_t)blockIdx.x * 16384;
    for (int i = threadIdx.x; i < 16384; i += 256) {
        int k5 = i & 31, n = (i >> 5) & 127, kb = i >> 12;
        D[i] = f2bf(S[(size_t)(kb * 32 + k5) * 128 + n]);
    }
}

// ---------------------------------------------------------------------------
// k0b: W_out [128][50000] fp32 -> WT [n][k] bf16
__global__ __launch_bounds__(256) void k0b_woutT(const float* __restrict__ W_out,
                                                 unsigned short* __restrict__ WT)
{
    int n  = blockIdx.x * 64 + (threadIdx.x >> 2);
    int k0 = (threadIdx.x & 3) * 32;
    if (n >= NC) return;
#pragma unroll 8
    for (int i = 0; i < 32; ++i)
        WT[(size_t)n * 128 + k0 + i] = f2bf(W_out[(size_t)(k0 + i) * NC + n]);
}

// ---------------------------------------------------------------------------
// MFMA helpers (16x16x32 bf16).  A-frag: lane holds A[m0+(lane&15)][kb*32+quad*8+j].
// B-frag (swizzled W): lane holds W[kb*32+quad*8+j][nt*16+(lane&15)].
// C/D: col = lane&15, row = quad*4 + reg.
__device__ __forceinline__ void gemm_k128(const unsigned short (*A)[136],
                                          int m0, int l16, int quad,
                                          const unsigned short* __restrict__ Wm,
                                          float4v acc[8]) {
#pragma unroll
    for (int kb = 0; kb < 4; ++kb) {
        short8v av = *(const short8v*)&A[m0 + l16][kb * 32 + quad * 8];
#pragma unroll
        for (int nt = 0; nt < 8; ++nt) {
            short8v bv = *(const short8v*)(Wm + (((kb * 128) + nt * 16 + l16) * 32 + quad * 8));
            acc[nt] = __builtin_amdgcn_mfma_f32_16x16x32_bf16(av, bv, acc[nt], 0, 0, 0);
        }
    }
}
// A-frags held in registers (gathered directly from the embedding tables).
__device__ __forceinline__ void gemm_reg(const short8v a[4], int l16, int quad,
                                         const unsigned short* __restrict__ Wm,
                                         float4v acc[8]) {
#pragma unroll
    for (int kb = 0; kb < 4; ++kb) {
#pragma unroll
        for (int nt = 0; nt < 8; ++nt) {
            short8v bv = *(const short8v*)(Wm + (((kb * 128) + nt * 16 + l16) * 32 + quad * 8));
            acc[nt] = __builtin_amdgcn_mfma_f32_16x16x32_bf16(a[kb], bv, acc[nt], 0, 0, 0);
        }
    }
}
__device__ __forceinline__ void zero8(float4v acc[8]) {
#pragma unroll
    for (int i = 0; i < 8; ++i) acc[i] = (float4v)0.0f;
}
// 8 contiguous f32 -> one bf16 A-frag word (16B)
__device__ __forceinline__ short8v cvt8(const float* __restrict__ p) {
    float4 v0 = *(const float4*)p;
    float4 v1 = *(const float4*)(p + 4);
    union { unsigned int u[4]; short8v s; } r;
    r.u[0] = pack2bf(v0.x, v0.y);
    r.u[1] = pack2bf(v0.z, v0.w);
    r.u[2] = pack2bf(v1.x, v1.y);
    r.u[3] = pack2bf(v1.z, v1.w);
    return r.s;
}

// ---------------------------------------------------------------------------
// k12: fused MFMA precompute.  grid = NTOK/64, block = 256 (4 waves),
// wave w owns tokens t0+16w .. t0+16w+15.  No barriers (all LDS is wave-local).
__global__ __launch_bounds__(256, 4) void k12_precompute(
    const int* __restrict__ item, const int* __restrict__ tix, const int* __restrict__ frq,
    const float* __restrict__ Ei, const float* __restrict__ Et, const float* __restrict__ Ef,
    const float* __restrict__ b_r, const float* __restrict__ b_z, const float* __restrict__ b_h,
    const float* __restrict__ b_tg, const float* __restrict__ b_fg,
    const float* __restrict__ b_delta, const float* __restrict__ b_f_dir, const float* __restrict__ b_psi,
    const unsigned short* __restrict__ WZ,
    float* __restrict__ PRE)
{
    __shared__ unsigned short Atg[64][136];   // tg (bf16, A-layout)
    __shared__ unsigned short Afg[64][136];   // fg (bf16, A-layout)

    const int t0   = blockIdx.x * 64;
    const int tid  = threadIdx.x;
    const int lane = tid & 63;
    const int wid  = tid >> 6;
    const int quad = lane >> 4;
    const int l16  = lane & 15;
    const int m0   = wid * 16;

    // --- gather embedding rows straight into register A-frags ---
    const int tok = t0 + m0 + l16;
    const int it  = item[tok], tt = tix[tok], ft = frq[tok];
    const float* pei = Ei + (size_t)it * U_ + quad * 8;
    const float* pet = Et + (size_t)tt * U_ + quad * 8;
    const float* pef = Ef + (size_t)ft * U_ + quad * 8;

    short8v axi[4], axt[4], axf[4];
#pragma unroll
    for (int kb = 0; kb < 4; ++kb) axi[kb] = cvt8(pei + kb * 32);
#pragma unroll
    for (int kb = 0; kb < 4; ++kb) axt[kb] = cvt8(pet + kb * 32);
#pragma unroll
    for (int kb = 0; kb < 4; ++kb) axf[kb] = cvt8(pef + kb * 32);

    const unsigned short* WM0  = WZ;                 // W_xtg
    const unsigned short* WM1  = WZ + 1  * 16384;    // W_tg
    const unsigned short* WM2  = WZ + 2  * 16384;    // W_xfg
    const unsigned short* WM3  = WZ + 3  * 16384;    // W_fg
    const unsigned short* WM4  = WZ + 4  * 16384;    // W_xr
    const unsigned short* WM5  = WZ + 5  * 16384;    // W_xz
    const unsigned short* WM6  = WZ + 6  * 16384;    // W_xh
    const unsigned short* WM7  = WZ + 7  * 16384;    // W_delta top (tg rows)
    const unsigned short* WM8  = WZ + 8  * 16384;    // W_delta bot (fg rows)
    const unsigned short* WM9  = WZ + 9  * 16384;    // W_f_dir
    const unsigned short* WM10 = WZ + 10 * 16384;    // W_psi

    float4v acc[8];
    const int tokbase = t0 + m0 + quad * 4;

    // ---- tg = sigmoid(xi@W_xtg + xt@W_tg + b_tg) -> Atg (bf16, A-layout) ----
    zero8(acc);
    gemm_reg(axi, l16, quad, WM0, acc);
    gemm_reg(axt, l16, quad, WM1, acc);
#pragma unroll
    for (int nt = 0; nt < 8; ++nt) {
        int n = nt * 16 + l16;
        float bb = b_tg[n];
#pragma unroll
        for (int r = 0; r < 4; ++r)
            Atg[m0 + quad * 4 + r][n] = f2bf(sigmoidf_(acc[nt][r] + bb));
    }
    // ---- fg = sigmoid(xi@W_xfg + xf@W_fg + b_fg) -> Afg ----
    zero8(acc);
    gemm_reg(axi, l16, quad, WM2, acc);
    gemm_reg(axf, l16, quad, WM3, acc);
#pragma unroll
    for (int nt = 0; nt < 8; ++nt) {
        int n = nt * 16 + l16;
        float bb = b_fg[n];
#pragma unroll
        for (int r = 0; r < 4; ++r)
            Afg[m0 + quad * 4 + r][n] = f2bf(sigmoidf_(acc[nt][r] + bb));
    }

    // ---- xr, xz, xh (xi only — hides the Atg/Afg LDS write->read latency) ----
    {
        const unsigned short* Wx[3] = { WM4, WM5, WM6 };
        const float* bx[3] = { b_r, b_z, b_h };
        const int    off[3] = { 128, 256, 384 };
#pragma unroll
        for (int m = 0; m < 3; ++m) {
            zero8(acc);
            gemm_reg(axi, l16, quad, Wx[m], acc);
#pragma unroll
            for (int nt = 0; nt < 8; ++nt) {
                int n = nt * 16 + l16;
                float bb = bx[m][n];
#pragma unroll
                for (int r = 0; r < 4; ++r)
                    PRE[(size_t)(tokbase + r) * 768 + off[m] + n] = acc[nt][r] + bb;
            }
        }
    }
    // ---- decay = exp(-softplus([tg|fg]@W_delta + b_delta)) ----
    zero8(acc);
    gemm_k128(Atg, m0, l16, quad, WM7, acc);
    gemm_k128(Afg, m0, l16, quad, WM8, acc);
#pragma unroll
    for (int nt = 0; nt < 8; ++nt) {
        int n = nt * 16 + l16;
        float bb = b_delta[n];
#pragma unroll
        for (int r = 0; r < 4; ++r)
            PRE[(size_t)(tokbase + r) * 768 + 0 + n] = expf(-softplusf_(acc[nt][r] + bb));
    }
    // ---- fdir = fg@W_f_dir + b ----
    zero8(acc);
    gemm_k128(Afg, m0, l16, quad, WM9, acc);
#pragma unroll
    for (int nt = 0; nt < 8; ++nt) {
        int n = nt * 16 + l16;
        float bb = b_f_dir[n];
#pragma unroll
        for (int r = 0; r < 4; ++r)
            PRE[(size_t)(tokbase + r) * 768 + 512 + n] = acc[nt][r] + bb;
    }
    // ---- psi = sigmoid(fg@W_psi + b) ----
    zero8(acc);
    gemm_k128(Afg, m0, l16, quad, WM10, acc);
#pragma unroll
    for (int nt = 0; nt < 8; ++nt) {
        int n = nt * 16 + l16;
        float bb = b_psi[n];
#pragma unroll
        for (int r = 0; r < 4; ++r)
            PRE[(size_t)(tokbase + r) * 768 + 640 + n] = sigmoidf_(acc[nt][r] + bb);
    }
}

// ---------------------------------------------------------------------------
// k3: one workgroup per batch row; 768 threads = 3 matrices x 256 threads.
//   tid>>8 : 0 -> W_hr, 1 -> W_hz, 2 -> W_hh
//   Within a matrix: thread owns 4 consecutive output cols x 16 k-rows
//   (col0 = (t&31)*4, kr = t>>5): 4 ds_read_b128 broadcasts instead of 16.
//   k-split is 8-way -> partials p*[8][128]; combines are 8 conflict-free
//   scalar reads by one 128-thread group.
//   Roles: B2: grp4 -> rh, grp0 -> zb.  C2: grp2 -> h update + Hb write.
//   Step: B(r,z partials) / B2(rh,zb) / C(h partials) / C2(h update) with
//   lgkm-only barriers; PRE prefetch stays in vmcnt flight.
__global__ __launch_bounds__(768, 2) void k3_scan(
    const float* __restrict__ PRE,
    const float* __restrict__ W_hr, const float* __restrict__ W_hz, const float* __restrict__ W_hh,
    unsigned short* __restrict__ Hb)
{
    const int b     = blockIdx.x;
    const int tid   = threadIdx.x;
    const int mat   = tid >> 8;         // 0: W_hr, 1: W_hz, 2: W_hh
    const int t     = tid & 255;
    const int col0  = (t & 31) << 2;    // 4 consecutive output columns
    const int kr    = t >> 5;           // k-range index, 8-way split
    const int kbase = kr << 4;          // [kbase, kbase+16)
    const int grp   = tid >> 7;         // 0..5 (128-thread combine roles)
    const int u     = tid & 127;

    const float* W = (mat == 0) ? W_hr : ((mat == 1) ? W_hz : W_hh);
    float wc[64];                       // wc[kk*4+c] = W[kbase+kk][col0+c]
#pragma unroll
    for (int k = 0; k < 16; ++k) {
        float4 wv = *(const float4*)&W[(size_t)(kbase + k) * U_ + col0];
        wc[k * 4 + 0] = wv.x; wc[k * 4 + 1] = wv.y;
        wc[k * 4 + 2] = wv.z; wc[k * 4 + 3] = wv.w;
    }
#pragma unroll
    for (int k = 0; k < 64; ++k) asm volatile("" : "+v"(wc[k]));   // pin in VGPRs

    __shared__ __align__(16) float hd[U_];
    __shared__ __align__(16) float rh[U_];
    __shared__ __align__(16) float zb[U_];
    __shared__ __align__(16) float pr[8][U_];
    __shared__ __align__(16) float pz[8][U_];
    __shared__ __align__(16) float ph[8][U_];
    if (tid < U_) hd[tid] = 0.f;    // h0 = 0 -> h_d(step 0) = 0

    const float* pre = PRE + (size_t)b * S_ * 768;
    // loop-carried per-group scalars (c*) and h state (grp 2 only)
    float c0 = 0.f, c1 = 0.f, c2 = 0.f, c3 = 0.f, hn = 0.f;
    {
        if (grp == 4)      c0 = pre[128 + u];                        // xr[0]
        else if (grp == 0) c0 = pre[256 + u];                        // xz[0]
        else if (grp == 2) { c0 = pre[384 + u]; c1 = pre[512 + u];   // xh, fdir
                             c2 = pre[640 + u];                      // psi
                             c3 = pre[768 + u]; }                    // decay[1]
    }
    bar_lds();

// 16k x 4col FMA block over vector VSRC, result -> DST[kr][col0..col0+3]
#define MATVEC16X4(VSRC, DST) do {                                          \
    float a0 = 0.f, a1 = 0.f, a2 = 0.f, a3 = 0.f;                           \
    _Pragma("unroll")                                                       \
    for (int q = 0; q < 4; ++q) {                                           \
        float4 hv = *(const float4*)&VSRC[kbase + 4 * q];                   \
        a0 = fmaf(hv.x, wc[(4*q+0)*4+0], a0);                               \
        a1 = fmaf(hv.x, wc[(4*q+0)*4+1], a1);                               \
        a2 = fmaf(hv.x, wc[(4*q+0)*4+2], a2);                               \
        a3 = fmaf(hv.x, wc[(4*q+0)*4+3], a3);                               \
        a0 = fmaf(hv.y, wc[(4*q+1)*4+0], a0);                               \
        a1 = fmaf(hv.y, wc[(4*q+1)*4+1], a1);                               \
        a2 = fmaf(hv.y, wc[(4*q+1)*4+2], a2);                               \
        a3 = fmaf(hv.y, wc[(4*q+1)*4+3], a3);                               \
        a0 = fmaf(hv.z, wc[(4*q+2)*4+0], a0);                               \
        a1 = fmaf(hv.z, wc[(4*q+2)*4+1], a1);                               \
        a2 = fmaf(hv.z, wc[(4*q+2)*4+2], a2);                               \
        a3 = fmaf(hv.z, wc[(4*q+2)*4+3], a3);                               \
        a0 = fmaf(hv.w, wc[(4*q+3)*4+0], a0);                               \
        a1 = fmaf(hv.w, wc[(4*q+3)*4+1], a1);                               \
        a2 = fmaf(hv.w, wc[(4*q+3)*4+2], a2);                               \
        a3 = fmaf(hv.w, wc[(4*q+3)*4+3], a3);                               \
    }                                                                       \
    float4 o_; o_.x = a0; o_.y = a1; o_.z = a2; o_.w = a3;                  \
    *(float4*)&DST[kr][col0] = o_;                                          \
} while (0)

    for (int s = 0; s < S_; ++s) {
        // prefetch step s+1 (left in vmcnt flight across all 4 barriers)
        float n0 = 0.f, n1 = 0.f, n2 = 0.f, n3 = 0.f;
        if (s + 1 < S_) {
            const float* p = pre + (size_t)(s + 1) * 768;
            if (grp == 4)      n0 = p[128 + u];
            else if (grp == 0) n0 = p[256 + u];
            else if (grp == 2) { n0 = p[384 + u]; n1 = p[512 + u]; n2 = p[640 + u];
                                 n3 = (s + 2 < S_) ? pre[(size_t)(s + 2) * 768 + u] : 0.f; }
        }

        // Phase B: r- and z-matvec partials over hd
        if (mat == 0)      MATVEC16X4(hd, pr);
        else if (mat == 1) MATVEC16X4(hd, pz);
        bar_lds();   // pr, pz ready

        // Phase B2: combine r (grp4) and z (grp0)
        if (grp == 4) {
            float srt = c0;
#pragma unroll
            for (int i = 0; i < 8; ++i) srt += pr[i][u];
            rh[u] = sigmoidf_(srt) * hd[u];
        } else if (grp == 0) {
            float szt = c0;
#pragma unroll
            for (int i = 0; i < 8; ++i) szt += pz[i][u];
            zb[u] = sigmoidf_(szt);
        }
        bar_lds();   // rh, zb ready

        // Phase C: h-matvec partials over rh
        if (mat == 2) MATVEC16X4(rh, ph);
        bar_lds();   // ph ready

        // Phase C2: h update (grp 2 only)
        if (grp == 2) {
            float mv2 = 0.f;
#pragma unroll
            for (int i = 0; i < 8; ++i) mv2 += ph[i][u];
            float hb = tanhf(c0 + mv2);
            float hf = tanhf(hb + c1);
            float hc = (1.f - c2) * hb + c2 * hf;
            float z  = zb[u];
            hn = (1.f - z) * hd[u] + z * hc;   // alpha==1 -> h_att = h_d
            hd[u] = c3 * hn;                    // decay[s+1] * h_new
        }
        bar_lds();   // hd ready for next step

        c0 = n0; c1 = n1; c2 = n2; c3 = n3;
    }
#undef MATVEC16X4
    if (grp == 2) Hb[(size_t)b * U_ + u] = f2bf(hn);
}

// ---------------------------------------------------------------------------
// k4a: logits = h @ W_out + b_out via bf16 MFMA.
__global__ __launch_bounds__(256) void k4a_logits(
    const unsigned short* __restrict__ Hb, const unsigned short* __restrict__ WT,
    const float* __restrict__ b_out, float* __restrict__ logits)
{
    const int tid  = threadIdx.x;
    const int lane = tid & 63, wid = tid >> 6;
    const int quad = lane >> 4, l16 = lane & 15;
    const int rb = blockIdx.y * 64 + wid * 16;
    const int cb = blockIdx.x * 128;

    short8v av[4];
#pragma unroll
    for (int kb = 0; kb < 4; ++kb)
        av[kb] = *(const short8v*)&Hb[(size_t)(rb + l16) * 128 + kb * 32 + quad * 8];

    float4v acc[8];
#pragma unroll
    for (int i = 0; i < 8; ++i) acc[i] = (float4v)0.0f;

#pragma unroll
    for (int kb = 0; kb < 4; ++kb) {
#pragma unroll
        for (int nt = 0; nt < 8; ++nt) {
            short8v bv = *(const short8v*)&WT[(size_t)(cb + nt * 16 + l16) * 128 + kb * 32 + quad * 8];
            acc[nt] = __builtin_amdgcn_mfma_f32_16x16x32_bf16(av[kb], bv, acc[nt], 0, 0, 0);
        }
    }
#pragma unroll
    for (int nt = 0; nt < 8; ++nt) {
        int n = cb + nt * 16 + l16;
        if (n < NC) {
            float bb = b_out[n];
#pragma unroll
            for (int r = 0; r < 4; ++r)
                logits[(size_t)(rb + quad * 4 + r) * NC + n] = acc[nt][r] + bb;
        }
    }
}

// ---------------------------------------------------------------------------
__global__ __launch_bounds__(256) void k4b_rowstats(
    const float* __restrict__ logits, float* __restrict__ rmax, float* __restrict__ rsum)
{
    const int r = blockIdx.x;
    const int tid = threadIdx.x;
    const float* row = logits + (size_t)r * NC;

    float m = -INFINITY, s = 0.f;
    for (int c = tid; c < NC; c += 256) {
        float x = row[c];
        float mn = fmaxf(m, x);
        s = s * expf(m - mn) + expf(x - mn);
        m = mn;
    }
    __shared__ float sm[256], ss[256];
    sm[tid] = m; ss[tid] = s;
    __syncthreads();
    for (int off = 128; off > 0; off >>= 1) {
        if (tid < off) {
            float m2 = sm[tid + off], s2 = ss[tid + off];
            float M = fmaxf(sm[tid], m2);
            ss[tid] = ss[tid] * expf(sm[tid] - M) + s2 * expf(m2 - M);
            sm[tid] = M;
        }
        __syncthreads();
    }
    if (tid == 0) { rmax[r] = sm[0]; rsum[r] = ss[0]; }
}

__global__ __launch_bounds__(256) void k4c_norm(
    const float* __restrict__ logits, const float* __restrict__ rmax,
    const float* __restrict__ rsum, float* __restrict__ out)
{
    const int r = blockIdx.y;
    const int c = blockIdx.x * 256 + threadIdx.x;
    if (c < NC) {
        size_t i = (size_t)r * NC + c;
        out[i] = expf(logits[i] - rmax[r]) / rsum[r];
    }
}

// ---------------------------------------------------------------------------
extern "C" void kernel_launch(void* const* d_in, const int* in_sizes, int n_in,
                              void* d_out, int out_size, void* d_ws, size_t ws_size,
                              hipStream_t stream) {
    const int*   item   = (const int*)d_in[0];
    const int*   tix    = (const int*)d_in[1];
    const int*   frq    = (const int*)d_in[2];
    const float* Ei     = (const float*)d_in[3];
    const float* Et     = (const float*)d_in[4];
    const float* Ef     = (const float*)d_in[5];
    const float* W_xr   = (const float*)d_in[6];
    const float* W_hr   = (const float*)d_in[7];
    const float* b_r    = (const float*)d_in[8];
    const float* W_xz   = (const float*)d_in[9];
    const float* W_hz   = (const float*)d_in[10];
    const float* b_z    = (const float*)d_in[11];
    const float* W_xh   = (const float*)d_in[12];
    const float* W_hh   = (const float*)d_in[13];
    const float* b_h    = (const float*)d_in[14];
    const float* W_xtg  = (const float*)d_in[15];
    const float* W_tg   = (const float*)d_in[16];
    const float* b_tg   = (const float*)d_in[17];
    const float* W_xfg  = (const float*)d_in[18];
    const float* W_fg   = (const float*)d_in[19];
    const float* b_fg   = (const float*)d_in[20];
    const float* W_delta= (const float*)d_in[21];
    const float* b_delta= (const float*)d_in[22];
    const float* W_f_dir= (const float*)d_in[23];
    const float* b_f_dir= (const float*)d_in[24];
    const float* W_psi  = (const float*)d_in[25];
    const float* b_psi  = (const float*)d_in[26];
    // d_in[27] = W_a — dead (softmax over singleton axis == 1)
    const float* W_out  = (const float*)d_in[28];
    const float* b_out  = (const float*)d_in[29];
    float* out = (float*)d_out;

    float* ws   = (float*)d_ws;
    float* PRE  = ws + PRE_OFF;
    float* LOG  = ws + LOG_OFF;
    unsigned short* WSWZ = (unsigned short*)(ws + WSWZ_OFF);
    unsigned short* WT   = (unsigned short*)(ws + PRE_OFF);   // aliases PRE (dead after k3)
    unsigned short* Hb   = (unsigned short*)(ws + HF_OFF);
    float* RMAX = ws + RMAX_OFF;
    float* RSUM = ws + RSUM_OFF;

    k0_wconv<<<12, 256, 0, stream>>>(
        W_xtg, W_tg, W_xfg, W_fg, W_xr, W_xz, W_xh,
        W_delta, W_delta + 128 * 128, W_f_dir, W_psi,
        W_psi /* pad slot 11, unused by k12 */, WSWZ);
    k12_precompute<<<NTOK / 64, 256, 0, stream>>>(
        item, tix, frq, Ei, Et, Ef,
        b_r, b_z, b_h, b_tg, b_fg, b_delta, b_f_dir, b_psi,
        WSWZ, PRE);
    k3_scan<<<B_, 768, 0, stream>>>(PRE, W_hr, W_hz, W_hh, Hb);
    k0b_woutT<<<(NC + 63) / 64, 256, 0, stream>>>(W_out, WT);
    k4a_logits<<<dim3((NC + 127) / 128, B_ / 64), 256, 0, stream>>>(Hb, WT, b_out, LOG);
    k4b_rowstats<<<B_, 256, 0, stream>>>(LOG, RMAX, RSUM);
    k4c_norm<<<dim3((NC + 255) / 256, B_), 256, 0, stream>>>(LOG, RMAX, RSUM, out);
}

// Round 3
// 624.425 us; speedup vs baseline: 1.4227x; 1.0939x over previous
//
#include <hip/hip_runtime.h>
#include <math.h>

// ---------------------------------------------------------------------------
// LongRec.  B=256, S=200, D=U=128, NC=50000.
// alpha = softmax over singleton axis == 1.0 -> h_att = h_d; W_a is dead.
// Pipeline:
//   k0  : 128x128 weights fp32 -> bf16 k-swizzled for MFMA B-frags
//   k12 : MFMA precompute -> PRE fp32 (reg A-frag gather; fast sigmoid epilog;
//         decay = exp(-softplus(y)) == sigmoid(-y) algebraically).
//   k3  : 200-step recurrence.  R8: wave-local matvecs + shfl_xor butterfly
//         reduction -> 2 barriers/step (was 4) and no LDS partial round-trips;
//         fast exp2/rcp sigmoid+tanh (libm tanhf chain was ~150cy on the
//         critical path).  512 thr = 8 waves: P1 = 4 r-waves + 4 z-waves,
//         P2 = all 8 waves on h-matvec + update.  k interleaved (16q+4*kg)
//         so the 4 k-groups hit distinct LDS banks.
//   k0b : W_out -> bf16 WT[n][k]  (aliases PRE, dead after k3)
//   k4a : logits = h @ W_out + b_out via bf16 MFMA
//   k4b/c: row stats, softmax normalize
// ---------------------------------------------------------------------------

#define B_  256
#define S_  200
#define U_  128
#define NC  50000
#define NTOK (B_ * S_)       // 51200

// ws layout (in floats)
#define PRE_OFF   0
#define PRE_SZ    (NTOK * 768)            // 39321600 floats
#define LOG_OFF   PRE_SZ                  // logits: 12.8M floats
#define WSWZ_OFF  (PRE_SZ + 12800000)     // bf16 weights: 12*16384 ushort
#define HF_OFF    (PRE_SZ + 13107200)
#define RMAX_OFF  (HF_OFF + B_ * U_)
#define RSUM_OFF  (RMAX_OFF + B_)
// WT (bf16 W_out^T) aliases PRE_OFF — PRE dead after k3; k0b runs after k3.

// PRE per-token layout: [decay(0) | xr(128) | xz(256) | xh(384) | fdir(512) | psi(640)]

typedef float  float4v  __attribute__((ext_vector_type(4)));
typedef short  short8v  __attribute__((ext_vector_type(8)));

// fast transcendentals: v_exp_f32 (2^x) + v_rcp_f32, ~2-3 ULP, branchless,
// correct saturation at +-inf (exp2 -> inf/0, rcp -> 0/1).
__device__ __forceinline__ float fsig(float x) {      // 1/(1+e^-x)
    return __builtin_amdgcn_rcpf(1.f + __builtin_amdgcn_exp2f(-1.4426950408889634f * x));
}
__device__ __forceinline__ float ftanh(float x) {     // 1 - 2/(e^{2x}+1)
    return 1.f - 2.f * __builtin_amdgcn_rcpf(1.f + __builtin_amdgcn_exp2f(2.8853900817779268f * x));
}
__device__ __forceinline__ unsigned short f2bf(float f) {   // RNE
    unsigned int u = __float_as_uint(f);
    u = (u + 0x7fffu + ((u >> 16) & 1u)) >> 16;
    return (unsigned short)u;
}
__device__ __forceinline__ unsigned int pack2bf(float a, float b) {
    return (unsigned int)f2bf(a) | ((unsigned int)f2bf(b) << 16);
}
// Barrier draining only LDS (lgkmcnt) — global prefetches stay in flight.
__device__ __forceinline__ void bar_lds() {
    asm volatile("s_waitcnt lgkmcnt(0)\n\ts_barrier" ::: "memory");
}

// ---------------------------------------------------------------------------
// k0: 12 x [128][128] fp32 -> bf16 swizzled  dst[((k>>5)*128 + n)*32 + (k&31)]
__global__ __launch_bounds__(256) void k0_wconv(
    const float* s0, const float* s1, const float* s2, const float* s3,
    const float* s4, const float* s5, const float* s6, const float* s7,
    const float* s8, const float* s9, const float* s10, const float* s11,
    unsigned short* __restrict__ dst)
{
    const float* srcs[12] = { s0,s1,s2,s3,s4,s5,s6,s7,s8,s9,s10,s11 };
    const float* S = srcs[blockIdx.x];
    unsigned short* D = dst + (size_t)blockIdx.x * 16384;
    for (int i = threadIdx.x; i < 16384; i += 256) {
        int k5 = i & 31, n = (i >> 5) & 127, kb = i >> 12;
        D[i] = f2bf(S[(size_t)(kb * 32 + k5) * 128 + n]);
    }
}

// ---------------------------------------------------------------------------
// k0b: W_out [128][50000] fp32 -> WT [n][k] bf16
__global__ __launch_bounds__(256) void k0b_woutT(const float* __restrict__ W_out,
                                                 unsigned short* __restrict__ WT)
{
    int n  = blockIdx.x * 64 + (threadIdx.x >> 2);
    int k0 = (threadIdx.x & 3) * 32;
    if (n >= NC) return;
#pragma unroll 8
    for (int i = 0; i < 32; ++i)
        WT[(size_t)n * 128 + k0 + i] = f2bf(W_out[(size_t)(k0 + i) * NC + n]);
}

// ---------------------------------------------------------------------------
// MFMA helpers (16x16x32 bf16).  A-frag: lane holds A[m0+(lane&15)][kb*32+quad*8+j].
// B-frag (swizzled W): lane holds W[kb*32+quad*8+j][nt*16+(lane&15)].
// C/D: col = lane&15, row = quad*4 + reg.
__device__ __forceinline__ void gemm_k128(const unsigned short (*A)[136],
                                          int m0, int l16, int quad,
                                          const unsigned short* __restrict__ Wm,
                                          float4v acc[8]) {
#pragma unroll
    for (int kb = 0; kb < 4; ++kb) {
        short8v av = *(const short8v*)&A[m0 + l16][kb * 32 + quad * 8];
#pragma unroll
        for (int nt = 0; nt < 8; ++nt) {
            short8v bv = *(const short8v*)(Wm + (((kb * 128) + nt * 16 + l16) * 32 + quad * 8));
            acc[nt] = __builtin_amdgcn_mfma_f32_16x16x32_bf16(av, bv, acc[nt], 0, 0, 0);
        }
    }
}
// A-frags held in registers (gathered directly from the embedding tables).
__device__ __forceinline__ void gemm_reg(const short8v a[4], int l16, int quad,
                                         const unsigned short* __restrict__ Wm,
                                         float4v acc[8]) {
#pragma unroll
    for (int kb = 0; kb < 4; ++kb) {
#pragma unroll
        for (int nt = 0; nt < 8; ++nt) {
            short8v bv = *(const short8v*)(Wm + (((kb * 128) + nt * 16 + l16) * 32 + quad * 8));
            acc[nt] = __builtin_amdgcn_mfma_f32_16x16x32_bf16(a[kb], bv, acc[nt], 0, 0, 0);
        }
    }
}
__device__ __forceinline__ void zero8(float4v acc[8]) {
#pragma unroll
    for (int i = 0; i < 8; ++i) acc[i] = (float4v)0.0f;
}
// 8 contiguous f32 -> one bf16 A-frag word (16B)
__device__ __forceinline__ short8v cvt8(const float* __restrict__ p) {
    float4 v0 = *(const float4*)p;
    float4 v1 = *(const float4*)(p + 4);
    union { unsigned int u[4]; short8v s; } r;
    r.u[0] = pack2bf(v0.x, v0.y);
    r.u[1] = pack2bf(v0.z, v0.w);
    r.u[2] = pack2bf(v1.x, v1.y);
    r.u[3] = pack2bf(v1.z, v1.w);
    return r.s;
}

// ---------------------------------------------------------------------------
// k12: fused MFMA precompute.  grid = NTOK/64, block = 256 (4 waves),
// wave w owns tokens t0+16w .. t0+16w+15.  No barriers (all LDS is wave-local).
__global__ __launch_bounds__(256, 4) void k12_precompute(
    const int* __restrict__ item, const int* __restrict__ tix, const int* __restrict__ frq,
    const float* __restrict__ Ei, const float* __restrict__ Et, const float* __restrict__ Ef,
    const float* __restrict__ b_r, const float* __restrict__ b_z, const float* __restrict__ b_h,
    const float* __restrict__ b_tg, const float* __restrict__ b_fg,
    const float* __restrict__ b_delta, const float* __restrict__ b_f_dir, const float* __restrict__ b_psi,
    const unsigned short* __restrict__ WZ,
    float* __restrict__ PRE)
{
    __shared__ unsigned short Atg[64][136];   // tg (bf16, A-layout)
    __shared__ unsigned short Afg[64][136];   // fg (bf16, A-layout)

    const int t0   = blockIdx.x * 64;
    const int tid  = threadIdx.x;
    const int lane = tid & 63;
    const int wid  = tid >> 6;
    const int quad = lane >> 4;
    const int l16  = lane & 15;
    const int m0   = wid * 16;

    // --- gather embedding rows straight into register A-frags ---
    const int tok = t0 + m0 + l16;
    const int it  = item[tok], tt = tix[tok], ft = frq[tok];
    const float* pei = Ei + (size_t)it * U_ + quad * 8;
    const float* pet = Et + (size_t)tt * U_ + quad * 8;
    const float* pef = Ef + (size_t)ft * U_ + quad * 8;

    short8v axi[4], axt[4], axf[4];
#pragma unroll
    for (int kb = 0; kb < 4; ++kb) axi[kb] = cvt8(pei + kb * 32);
#pragma unroll
    for (int kb = 0; kb < 4; ++kb) axt[kb] = cvt8(pet + kb * 32);
#pragma unroll
    for (int kb = 0; kb < 4; ++kb) axf[kb] = cvt8(pef + kb * 32);

    const unsigned short* WM0  = WZ;                 // W_xtg
    const unsigned short* WM1  = WZ + 1  * 16384;    // W_tg
    const unsigned short* WM2  = WZ + 2  * 16384;    // W_xfg
    const unsigned short* WM3  = WZ + 3  * 16384;    // W_fg
    const unsigned short* WM4  = WZ + 4  * 16384;    // W_xr
    const unsigned short* WM5  = WZ + 5  * 16384;    // W_xz
    const unsigned short* WM6  = WZ + 6  * 16384;    // W_xh
    const unsigned short* WM7  = WZ + 7  * 16384;    // W_delta top (tg rows)
    const unsigned short* WM8  = WZ + 8  * 16384;    // W_delta bot (fg rows)
    const unsigned short* WM9  = WZ + 9  * 16384;    // W_f_dir
    const unsigned short* WM10 = WZ + 10 * 16384;    // W_psi

    float4v acc[8];
    const int tokbase = t0 + m0 + quad * 4;

    // ---- tg = sigmoid(xi@W_xtg + xt@W_tg + b_tg) -> Atg (bf16, A-layout) ----
    zero8(acc);
    gemm_reg(axi, l16, quad, WM0, acc);
    gemm_reg(axt, l16, quad, WM1, acc);
#pragma unroll
    for (int nt = 0; nt < 8; ++nt) {
        int n = nt * 16 + l16;
        float bb = b_tg[n];
#pragma unroll
        for (int r = 0; r < 4; ++r)
            Atg[m0 + quad * 4 + r][n] = f2bf(fsig(acc[nt][r] + bb));
    }
    // ---- fg = sigmoid(xi@W_xfg + xf@W_fg + b_fg) -> Afg ----
    zero8(acc);
    gemm_reg(axi, l16, quad, WM2, acc);
    gemm_reg(axf, l16, quad, WM3, acc);
#pragma unroll
    for (int nt = 0; nt < 8; ++nt) {
        int n = nt * 16 + l16;
        float bb = b_fg[n];
#pragma unroll
        for (int r = 0; r < 4; ++r)
            Afg[m0 + quad * 4 + r][n] = f2bf(fsig(acc[nt][r] + bb));
    }

    // ---- xr, xz, xh (xi only — hides the Atg/Afg LDS write->read latency) ----
    {
        const unsigned short* Wx[3] = { WM4, WM5, WM6 };
        const float* bx[3] = { b_r, b_z, b_h };
        const int    off[3] = { 128, 256, 384 };
#pragma unroll
        for (int m = 0; m < 3; ++m) {
            zero8(acc);
            gemm_reg(axi, l16, quad, Wx[m], acc);
#pragma unroll
            for (int nt = 0; nt < 8; ++nt) {
                int n = nt * 16 + l16;
                float bb = bx[m][n];
#pragma unroll
                for (int r = 0; r < 4; ++r)
                    PRE[(size_t)(tokbase + r) * 768 + off[m] + n] = acc[nt][r] + bb;
            }
        }
    }
    // ---- decay = exp(-softplus(y)) == sigmoid(-y), y = [tg|fg]@W_delta + b ----
    zero8(acc);
    gemm_k128(Atg, m0, l16, quad, WM7, acc);
    gemm_k128(Afg, m0, l16, quad, WM8, acc);
#pragma unroll
    for (int nt = 0; nt < 8; ++nt) {
        int n = nt * 16 + l16;
        float bb = b_delta[n];
#pragma unroll
        for (int r = 0; r < 4; ++r)
            PRE[(size_t)(tokbase + r) * 768 + 0 + n] = fsig(-(acc[nt][r] + bb));
    }
    // ---- fdir = fg@W_f_dir + b ----
    zero8(acc);
    gemm_k128(Afg, m0, l16, quad, WM9, acc);
#pragma unroll
    for (int nt = 0; nt < 8; ++nt) {
        int n = nt * 16 + l16;
        float bb = b_f_dir[n];
#pragma unroll
        for (int r = 0; r < 4; ++r)
            PRE[(size_t)(tokbase + r) * 768 + 512 + n] = acc[nt][r] + bb;
    }
    // ---- psi = sigmoid(fg@W_psi + b) ----
    zero8(acc);
    gemm_k128(Afg, m0, l16, quad, WM10, acc);
#pragma unroll
    for (int nt = 0; nt < 8; ++nt) {
        int n = nt * 16 + l16;
        float bb = b_psi[n];
#pragma unroll
        for (int r = 0; r < 4; ++r)
            PRE[(size_t)(tokbase + r) * 768 + 640 + n] = fsig(acc[nt][r] + bb);
    }
}

// ---------------------------------------------------------------------------
// k3: one workgroup per batch row; 512 threads = 8 waves.
//   P1: waves 0-3 r-matvec, waves 4-7 z-matvec over hd.  Each wave owns 32
//       cols; lane owns 2 cols x 32 k (k interleaved: k = 16q + 4*kg + j so
//       the 4 k-groups read distinct LDS banks).  Reduction = shfl_xor
//       butterfly (16, 32) — NO LDS partials, NO combine phase.  Sigmoid +
//       (*hd for rh) in-register; lanes<16 write rh/zb.
//   P2: all 8 waves h-matvec over rh; wave owns 16 cols, lane owns 1 col x
//       32 k; butterfly reduce; tanh chain + blend in-register (8 waves run
//       the chains in parallel); lanes<16 write hd.
//   2 lgkm-only barriers/step (was 4); PRE prefetch stays in vmcnt flight.
__global__ __launch_bounds__(512, 2) void k3_scan(
    const float* __restrict__ PRE,
    const float* __restrict__ W_hr, const float* __restrict__ W_hz, const float* __restrict__ W_hh,
    unsigned short* __restrict__ Hb)
{
    const int b    = blockIdx.x;
    const int tid  = threadIdx.x;
    const int lane = tid & 63;
    const int wid  = tid >> 6;          // 0..7
    const int l15  = lane & 15;
    const int kg   = lane >> 4;         // 0..3 (k-group)

    const int colA = ((wid & 3) << 5) + (l15 << 1);   // P1: 2 cols, even
    const int colB = (wid << 4) + l15;                // P2: 1 col

    // --- loop-invariant weights pinned in VGPRs ---
    const float* Wrz = (wid < 4) ? W_hr : W_hz;
    float wrz[64];   // [(q*4+j)*2+c] = Wrz[16q+4kg+j][colA+c]
#pragma unroll
    for (int q = 0; q < 8; ++q)
#pragma unroll
        for (int j = 0; j < 4; ++j) {
            float2 wv = *(const float2*)&Wrz[(size_t)(16 * q + 4 * kg + j) * U_ + colA];
            wrz[(q * 4 + j) * 2 + 0] = wv.x;
            wrz[(q * 4 + j) * 2 + 1] = wv.y;
        }
    float whh[32];   // [q*4+j] = W_hh[16q+4kg+j][colB]
#pragma unroll
    for (int q = 0; q < 8; ++q)
#pragma unroll
        for (int j = 0; j < 4; ++j)
            whh[q * 4 + j] = W_hh[(size_t)(16 * q + 4 * kg + j) * U_ + colB];
#pragma unroll
    for (int k = 0; k < 64; ++k) asm volatile("" : "+v"(wrz[k]));
#pragma unroll
    for (int k = 0; k < 32; ++k) asm volatile("" : "+v"(whh[k]));

    __shared__ __align__(16) float hd[U_];
    __shared__ __align__(16) float rh[U_];
    __shared__ __align__(16) float zb[U_];
    if (tid < U_) hd[tid] = 0.f;    // h0 = 0 -> h_d(step 0) = 0

    const float* pre = PRE + (size_t)b * S_ * 768;
    // step-s constants (prefetched one step ahead, vmcnt flight across bars)
    float c_p0, c_p1, c_xh, c_fd, c_ps, c_dk;
    {
        float2 t = (wid < 4) ? *(const float2*)(pre + 128 + colA)
                             : *(const float2*)(pre + 256 + colA);
        c_p0 = t.x; c_p1 = t.y;
        c_xh = pre[384 + colB]; c_fd = pre[512 + colB]; c_ps = pre[640 + colB];
        c_dk = pre[768 + colB];                        // decay[1]
    }
    bar_lds();

    float hn = 0.f;
    for (int s = 0; s < S_; ++s) {
        // prefetch step s+1 constants (left in vmcnt flight)
        float n_p0 = 0.f, n_p1 = 0.f, n_xh = 0.f, n_fd = 0.f, n_ps = 0.f, n_dk = 0.f;
        if (s + 1 < S_) {
            const float* p = pre + (size_t)(s + 1) * 768;
            float2 t = (wid < 4) ? *(const float2*)(p + 128 + colA)
                                 : *(const float2*)(p + 256 + colA);
            n_p0 = t.x; n_p1 = t.y;
            n_xh = p[384 + colB]; n_fd = p[512 + colB]; n_ps = p[640 + colB];
            n_dk = (s + 2 < S_) ? pre[(size_t)(s + 2) * 768 + colB] : 0.f;
        }

        // ---- P1: r/z matvec over hd + in-wave reduce + sigmoid ----
        float2 hdA = *(const float2*)&hd[colA];   // for rh = sig(r)*hd
        float a0 = 0.f, a1 = 0.f;
#pragma unroll
        for (int q = 0; q < 8; ++q) {
            float4 hv = *(const float4*)&hd[16 * q + 4 * kg];
            a0 = fmaf(hv.x, wrz[(q * 4 + 0) * 2 + 0], a0); a1 = fmaf(hv.x, wrz[(q * 4 + 0) * 2 + 1], a1);
            a0 = fmaf(hv.y, wrz[(q * 4 + 1) * 2 + 0], a0); a1 = fmaf(hv.y, wrz[(q * 4 + 1) * 2 + 1], a1);
            a0 = fmaf(hv.z, wrz[(q * 4 + 2) * 2 + 0], a0); a1 = fmaf(hv.z, wrz[(q * 4 + 2) * 2 + 1], a1);
            a0 = fmaf(hv.w, wrz[(q * 4 + 3) * 2 + 0], a0); a1 = fmaf(hv.w, wrz[(q * 4 + 3) * 2 + 1], a1);
        }
        a0 += __shfl_xor(a0, 16); a0 += __shfl_xor(a0, 32);
        a1 += __shfl_xor(a1, 16); a1 += __shfl_xor(a1, 32);
        if (lane < 16) {
            float s0 = fsig(c_p0 + a0), s1 = fsig(c_p1 + a1);
            if (wid < 4) *(float2*)&rh[colA] = make_float2(s0 * hdA.x, s1 * hdA.y);
            else         *(float2*)&zb[colA] = make_float2(s0, s1);
        }
        bar_lds();   // rh, zb ready

        // ---- P2: h matvec over rh (all 8 waves) + update ----
        float z_  = zb[colB];
        float hd_ = hd[colB];
        float a2 = 0.f;
#pragma unroll
        for (int q = 0; q < 8; ++q) {
            float4 rv = *(const float4*)&rh[16 * q + 4 * kg];
            a2 = fmaf(rv.x, whh[q * 4 + 0], a2);
            a2 = fmaf(rv.y, whh[q * 4 + 1], a2);
            a2 = fmaf(rv.z, whh[q * 4 + 2], a2);
            a2 = fmaf(rv.w, whh[q * 4 + 3], a2);
        }
        a2 += __shfl_xor(a2, 16); a2 += __shfl_xor(a2, 32);
        float hb = ftanh(c_xh + a2);
        float hf = ftanh(hb + c_fd);
        float hc = (1.f - c_ps) * hb + c_ps * hf;
        hn = (1.f - z_) * hd_ + z_ * hc;          // alpha==1 -> h_att = h_d
        if (lane < 16) hd[colB] = c_dk * hn;      // decay[s+1] * h_new
        bar_lds();   // hd ready for next step

        c_p0 = n_p0; c_p1 = n_p1; c_xh = n_xh; c_fd = n_fd; c_ps = n_ps; c_dk = n_dk;
    }
    if (lane < 16) Hb[(size_t)b * U_ + colB] = f2bf(hn);
}

// ---------------------------------------------------------------------------
// k4a: logits = h @ W_out + b_out via bf16 MFMA.
__global__ __launch_bounds__(256) void k4a_logits(
    const unsigned short* __restrict__ Hb, const unsigned short* __restrict__ WT,
    const float* __restrict__ b_out, float* __restrict__ logits)
{
    const int tid  = threadIdx.x;
    const int lane = tid & 63, wid = tid >> 6;
    const int quad = lane >> 4, l16 = lane & 15;
    const int rb = blockIdx.y * 64 + wid * 16;
    const int cb = blockIdx.x * 128;

    short8v av[4];
#pragma unroll
    for (int kb = 0; kb < 4; ++kb)
        av[kb] = *(const short8v*)&Hb[(size_t)(rb + l16) * 128 + kb * 32 + quad * 8];

    float4v acc[8];
#pragma unroll
    for (int i = 0; i < 8; ++i) acc[i] = (float4v)0.0f;

#pragma unroll
    for (int kb = 0; kb < 4; ++kb) {
#pragma unroll
        for (int nt = 0; nt < 8; ++nt) {
            short8v bv = *(const short8v*)&WT[(size_t)(cb + nt * 16 + l16) * 128 + kb * 32 + quad * 8];
            acc[nt] = __builtin_amdgcn_mfma_f32_16x16x32_bf16(av[kb], bv, acc[nt], 0, 0, 0);
        }
    }
#pragma unroll
    for (int nt = 0; nt < 8; ++nt) {
        int n = cb + nt * 16 + l16;
        if (n < NC) {
            float bb = b_out[n];
#pragma unroll
            for (int r = 0; r < 4; ++r)
                logits[(size_t)(rb + quad * 4 + r) * NC + n] = acc[nt][r] + bb;
        }
    }
}

// ---------------------------------------------------------------------------
__global__ __launch_bounds__(256) void k4b_rowstats(
    const float* __restrict__ logits, float* __restrict__ rmax, float* __restrict__ rsum)
{
    const int r = blockIdx.x;
    const int tid = threadIdx.x;
    const float* row = logits + (size_t)r * NC;

    float m = -INFINITY, s = 0.f;
    for (int c = tid; c < NC; c += 256) {
        float x = row[c];
        float mn = fmaxf(m, x);
        s = s * expf(m - mn) + expf(x - mn);
        m = mn;
    }
    __shared__ float sm[256], ss[256];
    sm[tid] = m; ss[tid] = s;
    __syncthreads();
    for (int off = 128; off > 0; off >>= 1) {
        if (tid < off) {
            float m2 = sm[tid + off], s2 = ss[tid + off];
            float M = fmaxf(sm[tid], m2);
            ss[tid] = ss[tid] * expf(sm[tid] - M) + s2 * expf(m2 - M);
            sm[tid] = M;
        }
        __syncthreads();
    }
    if (tid == 0) { rmax[r] = sm[0]; rsum[r] = ss[0]; }
}

__global__ __launch_bounds__(256) void k4c_norm(
    const float* __restrict__ logits, const float* __restrict__ rmax,
    const float* __restrict__ rsum, float* __restrict__ out)
{
    const int r = blockIdx.y;
    const int c = blockIdx.x * 256 + threadIdx.x;
    if (c < NC) {
        size_t i = (size_t)r * NC + c;
        out[i] = expf(logits[i] - rmax[r]) / rsum[r];
    }
}

// ---------------------------------------------------------------------------
extern "C" void kernel_launch(void* const* d_in, const int* in_sizes, int n_in,
                              void* d_out, int out_size, void* d_ws, size_t ws_size,
                              hipStream_t stream) {
    const int*   item   = (const int*)d_in[0];
    const int*   tix    = (const int*)d_in[1];
    const int*   frq    = (const int*)d_in[2];
    const float* Ei     = (const float*)d_in[3];
    const float* Et     = (const float*)d_in[4];
    const float* Ef     = (const float*)d_in[5];
    const float* W_xr   = (const float*)d_in[6];
    const float* W_hr   = (const float*)d_in[7];
    const float* b_r    = (const float*)d_in[8];
    const float* W_xz   = (const float*)d_in[9];
    const float* W_hz   = (const float*)d_in[10];
    const float* b_z    = (const float*)d_in[11];
    const float* W_xh   = (const float*)d_in[12];
    const float* W_hh   = (const float*)d_in[13];
    const float* b_h    = (const float*)d_in[14];
    const float* W_xtg  = (const float*)d_in[15];
    const float* W_tg   = (const float*)d_in[16];
    const float* b_tg   = (const float*)d_in[17];
    const float* W_xfg  = (const float*)d_in[18];
    const float* W_fg   = (const float*)d_in[19];
    const float* b_fg   = (const float*)d_in[20];
    const float* W_delta= (const float*)d_in[21];
    const float* b_delta= (const float*)d_in[22];
    const float* W_f_dir= (const float*)d_in[23];
    const float* b_f_dir= (const float*)d_in[24];
    const float* W_psi  = (const float*)d_in[25];
    const float* b_psi  = (const float*)d_in[26];
    // d_in[27] = W_a — dead (softmax over singleton axis == 1)
    const float* W_out  = (const float*)d_in[28];
    const float* b_out  = (const float*)d_in[29];
    float* out = (float*)d_out;

    float* ws   = (float*)d_ws;
    float* PRE  = ws + PRE_OFF;
    float* LOG  = ws + LOG_OFF;
    unsigned short* WSWZ = (unsigned short*)(ws + WSWZ_OFF);
    unsigned short* WT   = (unsigned short*)(ws + PRE_OFF);   // aliases PRE (dead after k3)
    unsigned short* Hb   = (unsigned short*)(ws + HF_OFF);
    float* RMAX = ws + RMAX_OFF;
    float* RSUM = ws + RSUM_OFF;

    k0_wconv<<<12, 256, 0, stream>>>(
        W_xtg, W_tg, W_xfg, W_fg, W_xr, W_xz, W_xh,
        W_delta, W_delta + 128 * 128, W_f_dir, W_psi,
        W_psi /* pad slot 11, unused by k12 */, WSWZ);
    k12_precompute<<<NTOK / 64, 256, 0, stream>>>(
        item, tix, frq, Ei, Et, Ef,
        b_r, b_z, b_h, b_tg, b_fg, b_delta, b_f_dir, b_psi,
        WSWZ, PRE);
    k3_scan<<<B_, 512, 0, stream>>>(PRE, W_hr, W_hz, W_hh, Hb);
    k0b_woutT<<<(NC + 63) / 64, 256, 0, stream>>>(W_out, WT);
    k4a_logits<<<dim3((NC + 127) / 128, B_ / 64), 256, 0, stream>>>(Hb, WT, b_out, LOG);
    k4b_rowstats<<<B_, 256, 0, stream>>>(LOG, RMAX, RSUM);
    k4c_norm<<<dim3((NC + 255) / 256, B_), 256, 0, stream>>>(LOG, RMAX, RSUM, out);
}